// Round 6
// baseline (1655.447 us; speedup 1.0000x reference)
//
#include <hip/hip_runtime.h>
#include <hip/hip_bf16.h>

// RNN_80848464380442: B=64, S=2048, V=50257, E=128, H=256, C=2 (f32 in/out, x int32)
// Stage 1: xw[tok][sig(j)] = bU[j] + sum_e emb[x]*W  (fp16 to ws, sigma-permuted cols)
// Stage 2: MFMA scan, 4 blocks x 16 batch rows, 4 waves x 4 N-tiles (256 thr).
//          fp16 everywhere (8x less quant error than bf16, same MFMA rate).
//          U in regs as B-frags (via sigma^-1), h double-buffered in LDS (sigma order),
//          packed ds_write_b64 epilogue, 1 barrier/step.
// Stage 3: logits = h @ V + bV fused post-loop.
// sigma: j = 64w+16s+n  ->  p = 64w+4n+s   (lane writes s=0..3 contiguously)

#define HB 256
#define EB 128
#define SB 2048
#define BB 64
#define TPB 32
#define ROWS 16
#define PITCH 264   // u16/row = 528 B

typedef unsigned short u16;
typedef __attribute__((ext_vector_type(4))) float f32x4;
typedef __attribute__((ext_vector_type(8))) _Float16 f16x8;

__device__ __forceinline__ u16 f2h_bits(float f) {
    union { _Float16 h; u16 b; } x; x.h = (_Float16)f; return x.b;
}
__device__ __forceinline__ float h2f_bits(u16 b) {
    union { u16 b; _Float16 h; } x; x.b = b; return (float)x.h;
}

__device__ __forceinline__ int sig(int j)    { return (j & 0xC0) | ((j & 15) << 2) | ((j >> 4) & 3); }
__device__ __forceinline__ int invsig(int p) { return (p & 0xC0) | ((p & 3) << 4) | ((p >> 2) & 15); }

// ---------------- Stage 1: embed + project (32 tokens per 256-thread block) --------
__global__ __launch_bounds__(256) void embed_proj(
    const int* __restrict__ x, const float* __restrict__ emb,
    const float* __restrict__ W, const float* __restrict__ bU,
    u16* __restrict__ xw)
{
    __shared__ __align__(16) float el[TPB][EB];   // 16 KB
    __shared__ int toks[TPB];

    const int tid = threadIdx.x;
    const long base = (long)blockIdx.x * TPB;

    if (tid < TPB) toks[tid] = x[base + tid];
    __syncthreads();

    for (int r = 0; r < TPB * EB / 256; ++r) {
        int i = tid + r * 256;
        int row = i >> 7, e = i & (EB - 1);
        int u = toks[row];
        el[row][e] = (u == 0) ? 0.f : emb[(size_t)u * EB + e];   // padding_idx=0
    }
    __syncthreads();

    const int j = tid;
    const int sj = sig(j);
    const float bu = bU[j];
    float acc[TPB];
    #pragma unroll
    for (int t = 0; t < TPB; ++t) acc[t] = bu;

    for (int e0 = 0; e0 < EB; e0 += 4) {
        float w0 = W[(e0 + 0) * HB + j];
        float w1 = W[(e0 + 1) * HB + j];
        float w2 = W[(e0 + 2) * HB + j];
        float w3 = W[(e0 + 3) * HB + j];
        #pragma unroll
        for (int t = 0; t < TPB; ++t) {
            float4 ev = *(const float4*)&el[t][e0];
            acc[t] = fmaf(ev.x, w0, acc[t]);
            acc[t] = fmaf(ev.y, w1, acc[t]);
            acc[t] = fmaf(ev.z, w2, acc[t]);
            acc[t] = fmaf(ev.w, w3, acc[t]);
        }
    }
    #pragma unroll
    for (int t = 0; t < TPB; ++t)
        xw[(base + t) * HB + sj] = f2h_bits(acc[t]);
}

// ---------------- Stage 2+3: MFMA scan, 4 blocks x 256 threads (4 waves) -----------
__global__ __launch_bounds__(256, 1) void rnn_scan_mfma(
    const u16* __restrict__ xw, const float* __restrict__ U,
    const float* __restrict__ V, const float* __restrict__ bV,
    float* __restrict__ out)
{
    __shared__ __align__(16) u16 H[2][ROWS][PITCH];   // double-buffered h (fp16), sigma order

    const int tid  = threadIdx.x;
    const int lane = tid & 63;
    const int w    = tid >> 6;            // wave 0..3, owns N-tiles 4w..4w+3
    const int b0   = blockIdx.x * ROWS;

    {   // zero both H buffers (incl. pad)
        unsigned* hz = (unsigned*)H;
        for (int i = tid; i < 2 * ROWS * PITCH / 2; i += 256) hz[i] = 0u;
    }

    const int n  = lane & 15;             // A-m / B-n / D-col
    const int kg = lane >> 4;             // 0..3

    // ---- B-frag preload via sigma^-1: Bf[s][ks], tile nt=4w+s, col j_out=nt*16+n ----
    f16x8 Bf[4][8];
    #pragma unroll
    for (int s = 0; s < 4; ++s) {
        const int col = (4 * w + s) * 16 + n;
        #pragma unroll
        for (int ks = 0; ks < 8; ++ks) {
            union { f16x8 v; u16 h[8]; } tmp;
            #pragma unroll
            for (int e = 0; e < 8; ++e) {
                const int p = ks * 32 + kg * 8 + e;          // storage k
                const int jin = invsig(p);                   // actual contraction j
                tmp.h[e] = f2h_bits(U[(size_t)jin * HB + col]);
            }
            Bf[s][ks] = tmp.v;
        }
    }

    // ---- per-lane output mapping: rows kg*4+q, storage cols 64w+4n+(0..3) ----
    const int pbase = 64 * w + 4 * n;                        // sigma-packed col base
    unsigned gbase[4];                                       // xw u16 index, t=0
    uint2 xwc[4];
    #pragma unroll
    for (int q = 0; q < 4; ++q) {
        const int row = kg * 4 + q;
        gbase[q] = ((unsigned)(b0 + row) * SB) * HB + pbase;
        xwc[q] = *(const uint2*)&xw[gbase[q]];               // 4 fp16 (s=0..3), t=0
    }
    __syncthreads();

    for (int t = 0; t < SB; ++t) {
        const int cb = t & 1;
        const int nb = cb ^ 1;

        // xw prefetch for t+1 first (longest latency, consumed at next epilogue)
        const unsigned tn = (unsigned)((t + 1 < SB) ? t + 1 : t) * HB;
        uint2 xwn[4];
        #pragma unroll
        for (int q = 0; q < 4; ++q)
            xwn[q] = *(const uint2*)&xw[gbase[q] + tn];

        // A-frags: full 16 rows, m = n, k-storage contiguous
        f16x8 Af[8];
        #pragma unroll
        for (int ks = 0; ks < 8; ++ks) {
            uint4 av = *(const uint4*)&H[cb][n][ks * 32 + kg * 8];
            Af[ks] = __builtin_bit_cast(f16x8, av);
        }

        // 32 MFMAs: 4 independent chains (one per N-tile)
        f32x4 acc[4] = {{0.f,0.f,0.f,0.f},{0.f,0.f,0.f,0.f},{0.f,0.f,0.f,0.f},{0.f,0.f,0.f,0.f}};
        #pragma unroll
        for (int ks = 0; ks < 8; ++ks) {
            #pragma unroll
            for (int s = 0; s < 4; ++s)
                acc[s] = __builtin_amdgcn_mfma_f32_16x16x32_f16(Af[ks], Bf[s][ks], acc[s], 0, 0, 0);
        }

        // epilogue: tanh, pack 4 fp16, one ds_write_b64 per row
        #pragma unroll
        for (int q = 0; q < 4; ++q) {
            const int row = kg * 4 + q;
            float xv[4] = { h2f_bits((u16)(xwc[q].x & 0xffffu)), h2f_bits((u16)(xwc[q].x >> 16)),
                            h2f_bits((u16)(xwc[q].y & 0xffffu)), h2f_bits((u16)(xwc[q].y >> 16)) };
            float th[4];
            #pragma unroll
            for (int s = 0; s < 4; ++s) {
                float z = acc[s][q] + xv[s];
                float E = __expf(z + z);                     // tanh = 1 - 2/(e^2z + 1)
                th[s] = fmaf(-2.f, __builtin_amdgcn_rcpf(E + 1.f), 1.f);
            }
            unsigned pk0 = (unsigned)f2h_bits(th[0]) | ((unsigned)f2h_bits(th[1]) << 16);
            unsigned pk1 = (unsigned)f2h_bits(th[2]) | ((unsigned)f2h_bits(th[3]) << 16);
            *(uint2*)&H[nb][row][pbase] = make_uint2(pk0, pk1);
            if (t == SB - 1) {                               // exact f32 h output
                #pragma unroll
                for (int s = 0; s < 4; ++s)
                    out[BB * 2 + (size_t)(b0 + row) * HB + (4 * w + s) * 16 + n] = th[s];
            }
            xwc[q] = xwn[q];
        }
        __syncthreads();
    }

    // logits from h_final in H[0] (SB even): 256 threads = 16 rows x 16 partials
    {
        const int r = tid >> 4, part = tid & 15;
        float s0 = 0.f, s1 = 0.f;
        #pragma unroll
        for (int i = 0; i < 16; ++i) {
            const int p = part * 16 + i;
            const int j = invsig(p);
            float hh = h2f_bits(H[0][r][p]);
            s0 = fmaf(hh, V[j * 2 + 0], s0);
            s1 = fmaf(hh, V[j * 2 + 1], s1);
        }
        #pragma unroll
        for (int o = 8; o > 0; o >>= 1) {
            s0 += __shfl_down(s0, o, 16);
            s1 += __shfl_down(s1, o, 16);
        }
        if (part == 0) {
            out[(size_t)(b0 + r) * 2 + 0] = s0 + bV[0];
            out[(size_t)(b0 + r) * 2 + 1] = s1 + bV[1];
        }
    }
}

extern "C" void kernel_launch(void* const* d_in, const int* in_sizes, int n_in,
                              void* d_out, int out_size, void* d_ws, size_t ws_size,
                              hipStream_t stream) {
    const int*   x   = (const int*)d_in[0];
    const float* emb = (const float*)d_in[1];
    const float* W   = (const float*)d_in[2];
    const float* U   = (const float*)d_in[3];
    const float* bU  = (const float*)d_in[4];
    const float* V   = (const float*)d_in[5];
    const float* bV  = (const float*)d_in[6];
    float* out = (float*)d_out;
    u16*   xw  = (u16*)d_ws;   // 64 MiB fp16 scratch, sigma-permuted columns

    embed_proj<<<BB * SB / TPB, 256, 0, stream>>>(x, emb, W, bU, xw);
    rnn_scan_mfma<<<BB / ROWS, 256, 0, stream>>>(xw, U, V, bV, out);
}

// Round 8
// 1604.180 us; speedup vs baseline: 1.0320x; 1.0320x over previous
//
#include <hip/hip_runtime.h>
#include <hip/hip_bf16.h>

// RNN_80848464380442: B=64, S=2048, V=50257, E=128, H=256, C=2 (f32 in/out, x int32)
// Stage 1: xw[tok][sig(j)] = bU[j] + sum_e emb[x]*W  (fp16 to ws, sigma-permuted cols)
// Stage 2: MFMA scan, 4 blocks x 16 batch rows, 4 waves x 4 N-tiles (256 thr), fp16.
//          U in regs as B-frags (via sigma^-1), h double-buffered in LDS (sigma order),
//          2-step-deep global xw prefetch ring (hides L3/HBM latency), 1 barrier/step.
// Stage 3: logits + h output post-loop from LDS.
// sigma: j = 64w+16s+n  ->  p = 64w+4n+s   (lane writes s=0..3 contiguously)

#define HB 256
#define EB 128
#define SB 2048
#define BB 64
#define TPB 32
#define ROWS 16
#define PITCH 264   // u16/row = 528 B; balanced 8-quad coverage on b128 reads

typedef unsigned short u16;
typedef __attribute__((ext_vector_type(4))) float f32x4;
typedef __attribute__((ext_vector_type(8))) _Float16 f16x8;
typedef __attribute__((ext_vector_type(2))) __fp16 fp16x2_t;   // cvt_pkrtz native type

__device__ __forceinline__ u16 f2h_bits(float f) {
    union { _Float16 h; u16 b; } x; x.h = (_Float16)f; return x.b;
}
__device__ __forceinline__ float h2f_bits(u16 b) {
    union { u16 b; _Float16 h; } x; x.b = b; return (float)x.h;
}
__device__ __forceinline__ float tanh_fast(float z) {
    float E = __expf(z + z);                       // tanh = 1 - 2/(e^2z + 1)
    return fmaf(-2.f, __builtin_amdgcn_rcpf(E + 1.f), 1.f);
}
__device__ __forceinline__ unsigned pkrtz(float a, float b) {
    fp16x2_t p = __builtin_amdgcn_cvt_pkrtz(a, b);
    return __builtin_bit_cast(unsigned, p);
}

__device__ __forceinline__ int sig(int j)    { return (j & 0xC0) | ((j & 15) << 2) | ((j >> 4) & 3); }
__device__ __forceinline__ int invsig(int p) { return (p & 0xC0) | ((p & 3) << 4) | ((p >> 2) & 15); }

// ---------------- Stage 1: embed + project (32 tokens per 256-thread block) --------
__global__ __launch_bounds__(256) void embed_proj(
    const int* __restrict__ x, const float* __restrict__ emb,
    const float* __restrict__ W, const float* __restrict__ bU,
    u16* __restrict__ xw)
{
    __shared__ __align__(16) float el[TPB][EB];   // 16 KB
    __shared__ int toks[TPB];

    const int tid = threadIdx.x;
    const long base = (long)blockIdx.x * TPB;

    if (tid < TPB) toks[tid] = x[base + tid];
    __syncthreads();

    for (int r = 0; r < TPB * EB / 256; ++r) {
        int i = tid + r * 256;
        int row = i >> 7, e = i & (EB - 1);
        int u = toks[row];
        el[row][e] = (u == 0) ? 0.f : emb[(size_t)u * EB + e];   // padding_idx=0
    }
    __syncthreads();

    const int j = tid;
    const int sj = sig(j);
    const float bu = bU[j];
    float acc[TPB];
    #pragma unroll
    for (int t = 0; t < TPB; ++t) acc[t] = bu;

    for (int e0 = 0; e0 < EB; e0 += 4) {
        float w0 = W[(e0 + 0) * HB + j];
        float w1 = W[(e0 + 1) * HB + j];
        float w2 = W[(e0 + 2) * HB + j];
        float w3 = W[(e0 + 3) * HB + j];
        #pragma unroll
        for (int t = 0; t < TPB; ++t) {
            float4 ev = *(const float4*)&el[t][e0];
            acc[t] = fmaf(ev.x, w0, acc[t]);
            acc[t] = fmaf(ev.y, w1, acc[t]);
            acc[t] = fmaf(ev.z, w2, acc[t]);
            acc[t] = fmaf(ev.w, w3, acc[t]);
        }
    }
    #pragma unroll
    for (int t = 0; t < TPB; ++t)
        xw[(base + t) * HB + sj] = f2h_bits(acc[t]);
}

// ---------------- Stage 2+3: MFMA scan, 4 blocks x 256 threads (4 waves) -----------
// STEP(T, X): consume xw buffer X (holds step T), immediately reissue X <- xw[T+2].
#define STEP(T, X)                                                                 \
  {                                                                                \
    const int cb = (T) & 1, nb = cb ^ 1;                                           \
    float xv[16];                                                                  \
    _Pragma("unroll")                                                              \
    for (int q = 0; q < 4; ++q) {                                                  \
        xv[4 * q + 0] = h2f_bits((u16)(X[q].x & 0xffffu));                         \
        xv[4 * q + 1] = h2f_bits((u16)(X[q].x >> 16));                             \
        xv[4 * q + 2] = h2f_bits((u16)(X[q].y & 0xffffu));                         \
        xv[4 * q + 3] = h2f_bits((u16)(X[q].y >> 16));                             \
    }                                                                              \
    {                                                                              \
        const unsigned toff = (unsigned)(((T) + 2 < SB) ? (T) + 2 : SB - 1) * HB;  \
        _Pragma("unroll")                                                          \
        for (int q = 0; q < 4; ++q)                                                \
            X[q] = *(const uint2*)&xw[gbase[q] + toff];                            \
    }                                                                              \
    f16x8 Af[8];                                                                   \
    _Pragma("unroll")                                                              \
    for (int ks = 0; ks < 8; ++ks) {                                               \
        uint4 av = *(const uint4*)&H[cb][n][ks * 32 + kg * 8];                     \
        Af[ks] = __builtin_bit_cast(f16x8, av);                                    \
    }                                                                              \
    f32x4 acc0 = {0.f,0.f,0.f,0.f}, acc1 = {0.f,0.f,0.f,0.f};                      \
    f32x4 acc2 = {0.f,0.f,0.f,0.f}, acc3 = {0.f,0.f,0.f,0.f};                      \
    _Pragma("unroll")                                                              \
    for (int ks = 0; ks < 8; ++ks) {                                               \
        acc0 = __builtin_amdgcn_mfma_f32_16x16x32_f16(Af[ks], Bf[0][ks], acc0, 0, 0, 0); \
        acc1 = __builtin_amdgcn_mfma_f32_16x16x32_f16(Af[ks], Bf[1][ks], acc1, 0, 0, 0); \
        acc2 = __builtin_amdgcn_mfma_f32_16x16x32_f16(Af[ks], Bf[2][ks], acc2, 0, 0, 0); \
        acc3 = __builtin_amdgcn_mfma_f32_16x16x32_f16(Af[ks], Bf[3][ks], acc3, 0, 0, 0); \
    }                                                                              \
    _Pragma("unroll")                                                              \
    for (int q = 0; q < 4; ++q) {                                                  \
        const int row = kg * 4 + q;                                                \
        float th0 = tanh_fast(acc0[q] + xv[4 * q + 0]);                            \
        float th1 = tanh_fast(acc1[q] + xv[4 * q + 1]);                            \
        float th2 = tanh_fast(acc2[q] + xv[4 * q + 2]);                            \
        float th3 = tanh_fast(acc3[q] + xv[4 * q + 3]);                            \
        *(uint2*)&H[nb][row][pbase] = make_uint2(pkrtz(th0, th1), pkrtz(th2, th3)); \
    }                                                                              \
    __syncthreads();                                                               \
  }

__global__ __launch_bounds__(256, 1) void rnn_scan_mfma(
    const u16* __restrict__ xw, const float* __restrict__ U,
    const float* __restrict__ V, const float* __restrict__ bV,
    float* __restrict__ out)
{
    __shared__ __align__(16) u16 H[2][ROWS][PITCH];   // double-buffered h (fp16), sigma order

    const int tid  = threadIdx.x;
    const int lane = tid & 63;
    const int w    = tid >> 6;            // wave 0..3, owns N-tiles 4w..4w+3
    const int b0   = blockIdx.x * ROWS;

    {   // zero both H buffers (incl. pad)
        unsigned* hz = (unsigned*)H;
        for (int i = tid; i < 2 * ROWS * PITCH / 2; i += 256) hz[i] = 0u;
    }

    const int n  = lane & 15;             // A-m / B-n / D-col
    const int kg = lane >> 4;             // 0..3

    // ---- B-frag preload via sigma^-1: Bf[s][ks], tile nt=4w+s, col j_out=nt*16+n ----
    f16x8 Bf[4][8];
    #pragma unroll
    for (int s = 0; s < 4; ++s) {
        const int col = (4 * w + s) * 16 + n;
        #pragma unroll
        for (int ks = 0; ks < 8; ++ks) {
            union { f16x8 v; u16 h[8]; } tmp;
            #pragma unroll
            for (int e = 0; e < 8; ++e) {
                const int p = ks * 32 + kg * 8 + e;          // storage k
                const int jin = invsig(p);                   // actual contraction j
                tmp.h[e] = f2h_bits(U[(size_t)jin * HB + col]);
            }
            Bf[s][ks] = tmp.v;
        }
    }

    // ---- per-lane output mapping: rows kg*4+q, storage cols 64w+4n+(0..3) ----
    const int pbase = 64 * w + 4 * n;                        // sigma-packed col base
    unsigned gbase[4];                                       // xw u16 index, t=0
    uint2 XA[4], XB[4];
    #pragma unroll
    for (int q = 0; q < 4; ++q) {
        const int row = kg * 4 + q;
        gbase[q] = ((unsigned)(b0 + row) * SB) * HB + pbase;
        XA[q] = *(const uint2*)&xw[gbase[q]];                // t = 0
        XB[q] = *(const uint2*)&xw[gbase[q] + HB];           // t = 1
    }
    __syncthreads();

    for (int t = 0; t < SB; t += 2) {
        STEP(t,     XA);
        STEP(t + 1, XB);
    }

    // h output (f32 from fp16 H[0]; SB even -> final h in buffer 0)
    for (int i = tid; i < ROWS * HB; i += 256) {
        const int r = i >> 8, p = i & 255;
        out[BB * 2 + (size_t)(b0 + r) * HB + invsig(p)] = h2f_bits(H[0][r][p]);
    }

    // logits: 256 threads = 16 rows x 16 partials
    {
        const int r = tid >> 4, part = tid & 15;
        float s0 = 0.f, s1 = 0.f;
        #pragma unroll
        for (int i = 0; i < 16; ++i) {
            const int p = part * 16 + i;
            const int j = invsig(p);
            float hh = h2f_bits(H[0][r][p]);
            s0 = fmaf(hh, V[j * 2 + 0], s0);
            s1 = fmaf(hh, V[j * 2 + 1], s1);
        }
        #pragma unroll
        for (int o = 8; o > 0; o >>= 1) {
            s0 += __shfl_down(s0, o, 16);
            s1 += __shfl_down(s1, o, 16);
        }
        if (part == 0) {
            out[(size_t)(b0 + r) * 2 + 0] = s0 + bV[0];
            out[(size_t)(b0 + r) * 2 + 1] = s1 + bV[1];
        }
    }
}

extern "C" void kernel_launch(void* const* d_in, const int* in_sizes, int n_in,
                              void* d_out, int out_size, void* d_ws, size_t ws_size,
                              hipStream_t stream) {
    const int*   x   = (const int*)d_in[0];
    const float* emb = (const float*)d_in[1];
    const float* W   = (const float*)d_in[2];
    const float* U   = (const float*)d_in[3];
    const float* bU  = (const float*)d_in[4];
    const float* V   = (const float*)d_in[5];
    const float* bV  = (const float*)d_in[6];
    float* out = (float*)d_out;
    u16*   xw  = (u16*)d_ws;   // 64 MiB fp16 scratch, sigma-permuted columns

    embed_proj<<<BB * SB / TPB, 256, 0, stream>>>(x, emb, W, bU, xw);
    rnn_scan_mfma<<<BB / ROWS, 256, 0, stream>>>(xw, U, V, bV, out);
}

// Round 9
// 1404.103 us; speedup vs baseline: 1.1790x; 1.1425x over previous
//
#include <hip/hip_runtime.h>
#include <hip/hip_bf16.h>

// RNN_80848464380442: B=64, S=2048, V=50257, E=128, H=256, C=2 (f32 in/out, x int32)
// Stage 1: xw[tok][sig(j)] = bU[j] + sum_e emb[x]*W  (fp16 to ws, sigma-permuted cols)
// Stage 2: MFMA scan, 4 blocks x 16 batch rows, 8 waves x 2 N-tiles (512 thr, 2 w/SIMD).
//          fp16; U in regs as B-frags (via sigma^-1); h double-buffered in LDS;
//          xw folded into MFMA C-input; 2-step-deep global prefetch ring; 1 barrier/step.
// Stage 3: logits + h output post-loop from LDS.
// sigma: j = 32w+16s+n  ->  p = 32w+2n+s   (lane's pair (tile0,tile1) is contiguous)

#define HB 256
#define EB 128
#define SB 2048
#define BB 64
#define TPB 32
#define ROWS 16
#define PITCH 264   // u16/row = 528 B

typedef unsigned short u16;
typedef __attribute__((ext_vector_type(4))) float f32x4;
typedef __attribute__((ext_vector_type(8))) _Float16 f16x8;

__device__ __forceinline__ u16 f2h_bits(float f) {
    union { _Float16 h; u16 b; } x; x.h = (_Float16)f; return x.b;
}
__device__ __forceinline__ float h2f_bits(u16 b) {
    union { u16 b; _Float16 h; } x; x.b = b; return (float)x.h;
}
__device__ __forceinline__ float tanh_fast(float z) {
    float E = __expf(z + z);                       // tanh = 1 - 2/(e^2z + 1)
    return fmaf(-2.f, __builtin_amdgcn_rcpf(E + 1.f), 1.f);
}

__device__ __forceinline__ int sig(int j)    { return (j & 0xE0) | ((j & 15) << 1) | ((j >> 4) & 1); }
__device__ __forceinline__ int invsig(int p) { return (p & 0xE0) | ((p & 1) << 4) | ((p >> 1) & 15); }

// ---------------- Stage 1: embed + project (32 tokens per 256-thread block) --------
__global__ __launch_bounds__(256) void embed_proj(
    const int* __restrict__ x, const float* __restrict__ emb,
    const float* __restrict__ W, const float* __restrict__ bU,
    u16* __restrict__ xw)
{
    __shared__ __align__(16) float el[TPB][EB];   // 16 KB
    __shared__ int toks[TPB];

    const int tid = threadIdx.x;
    const long base = (long)blockIdx.x * TPB;

    if (tid < TPB) toks[tid] = x[base + tid];
    __syncthreads();

    for (int r = 0; r < TPB * EB / 256; ++r) {
        int i = tid + r * 256;
        int row = i >> 7, e = i & (EB - 1);
        int u = toks[row];
        el[row][e] = (u == 0) ? 0.f : emb[(size_t)u * EB + e];   // padding_idx=0
    }
    __syncthreads();

    const int j = tid;
    const int sj = sig(j);
    const float bu = bU[j];
    float acc[TPB];
    #pragma unroll
    for (int t = 0; t < TPB; ++t) acc[t] = bu;

    for (int e0 = 0; e0 < EB; e0 += 4) {
        float w0 = W[(e0 + 0) * HB + j];
        float w1 = W[(e0 + 1) * HB + j];
        float w2 = W[(e0 + 2) * HB + j];
        float w3 = W[(e0 + 3) * HB + j];
        #pragma unroll
        for (int t = 0; t < TPB; ++t) {
            float4 ev = *(const float4*)&el[t][e0];
            acc[t] = fmaf(ev.x, w0, acc[t]);
            acc[t] = fmaf(ev.y, w1, acc[t]);
            acc[t] = fmaf(ev.z, w2, acc[t]);
            acc[t] = fmaf(ev.w, w3, acc[t]);
        }
    }
    #pragma unroll
    for (int t = 0; t < TPB; ++t)
        xw[(base + t) * HB + sj] = f2h_bits(acc[t]);
}

// ---------------- Stage 2+3: MFMA scan, 4 blocks x 512 threads (8 waves) -----------
// STEP(T, X): X holds step T's xw pair-words; init accs from X, reissue X <- T+2,
// read A-frags, 16 MFMAs (C-in = xw), tanh, packed RNE write, barrier.
#define STEP(T, X)                                                                 \
  {                                                                                \
    const int cb = (T) & 1, nb = cb ^ 1;                                           \
    f32x4 acc0, acc1;                                                              \
    _Pragma("unroll")                                                              \
    for (int q = 0; q < 4; ++q) {                                                  \
        acc0[q] = h2f_bits((u16)(X[q] & 0xffffu));                                 \
        acc1[q] = h2f_bits((u16)(X[q] >> 16));                                     \
    }                                                                              \
    {                                                                              \
        const unsigned toff = (unsigned)(((T) + 2 < SB) ? (T) + 2 : SB - 1) * HB;  \
        _Pragma("unroll")                                                          \
        for (int q = 0; q < 4; ++q)                                                \
            X[q] = *(const unsigned*)&xw[gbase[q] + toff];                         \
    }                                                                              \
    f16x8 Af[8];                                                                   \
    _Pragma("unroll")                                                              \
    for (int ks = 0; ks < 8; ++ks) {                                               \
        uint4 av = *(const uint4*)&H[cb][n][ks * 32 + kg * 8];                     \
        Af[ks] = __builtin_bit_cast(f16x8, av);                                    \
    }                                                                              \
    _Pragma("unroll")                                                              \
    for (int ks = 0; ks < 8; ++ks) {                                               \
        acc0 = __builtin_amdgcn_mfma_f32_16x16x32_f16(Af[ks], Bf[0][ks], acc0, 0, 0, 0); \
        acc1 = __builtin_amdgcn_mfma_f32_16x16x32_f16(Af[ks], Bf[1][ks], acc1, 0, 0, 0); \
    }                                                                              \
    _Pragma("unroll")                                                              \
    for (int q = 0; q < 4; ++q) {                                                  \
        float th0 = tanh_fast(acc0[q]);                                            \
        float th1 = tanh_fast(acc1[q]);                                            \
        unsigned pk = (unsigned)f2h_bits(th0) | ((unsigned)f2h_bits(th1) << 16);   \
        *(unsigned*)&H[nb][kg * 4 + q][pbase] = pk;                                \
    }                                                                              \
    __syncthreads();                                                               \
  }

__global__ __launch_bounds__(512, 2) void rnn_scan_mfma(
    const u16* __restrict__ xw, const float* __restrict__ U,
    const float* __restrict__ V, const float* __restrict__ bV,
    float* __restrict__ out)
{
    __shared__ __align__(16) u16 H[2][ROWS][PITCH];   // double-buffered h (fp16), sigma order

    const int tid  = threadIdx.x;
    const int lane = tid & 63;
    const int w    = tid >> 6;            // wave 0..7, owns N-tiles 2w, 2w+1
    const int b0   = blockIdx.x * ROWS;

    {   // zero both H buffers (incl. pad)
        unsigned* hz = (unsigned*)H;
        for (int i = tid; i < 2 * ROWS * PITCH / 2; i += 512) hz[i] = 0u;
    }

    const int n  = lane & 15;             // A-m / B-n / D-col
    const int kg = lane >> 4;             // 0..3

    // ---- B-frag preload via sigma^-1: Bf[s][ks], tile nt=2w+s, col j_out=nt*16+n ----
    f16x8 Bf[2][8];
    #pragma unroll
    for (int s = 0; s < 2; ++s) {
        const int col = (2 * w + s) * 16 + n;
        #pragma unroll
        for (int ks = 0; ks < 8; ++ks) {
            union { f16x8 v; u16 h[8]; } tmp;
            #pragma unroll
            for (int e = 0; e < 8; ++e) {
                const int p = ks * 32 + kg * 8 + e;          // storage k
                const int jin = invsig(p);                   // actual contraction j
                tmp.h[e] = f2h_bits(U[(size_t)jin * HB + col]);
            }
            Bf[s][ks] = tmp.v;
        }
    }

    // ---- per-lane mapping: rows kg*4+q, storage col pair at pbase = 32w+2n ----
    const int pbase = 32 * w + 2 * n;
    unsigned gbase[4];
    unsigned XA[4], XB[4];
    #pragma unroll
    for (int q = 0; q < 4; ++q) {
        const int row = kg * 4 + q;
        gbase[q] = ((unsigned)(b0 + row) * SB) * HB + pbase;
        XA[q] = *(const unsigned*)&xw[gbase[q]];             // t = 0
        XB[q] = *(const unsigned*)&xw[gbase[q] + HB];        // t = 1
    }
    __syncthreads();

    for (int t = 0; t < SB; t += 2) {
        STEP(t,     XA);
        STEP(t + 1, XB);
    }

    // h output (f32 from fp16 H[0]; SB even -> final h in buffer 0)
    for (int i = tid; i < ROWS * HB; i += 512) {
        const int r = i >> 8, p = i & 255;
        out[BB * 2 + (size_t)(b0 + r) * HB + invsig(p)] = h2f_bits(H[0][r][p]);
    }

    // logits: first 256 threads = 16 rows x 16 partials
    if (tid < ROWS * 16) {
        const int r = tid >> 4, part = tid & 15;
        float s0 = 0.f, s1 = 0.f;
        #pragma unroll
        for (int i = 0; i < 16; ++i) {
            const int p = part * 16 + i;
            const int j = invsig(p);
            float hh = h2f_bits(H[0][r][p]);
            s0 = fmaf(hh, V[j * 2 + 0], s0);
            s1 = fmaf(hh, V[j * 2 + 1], s1);
        }
        #pragma unroll
        for (int o = 8; o > 0; o >>= 1) {
            s0 += __shfl_down(s0, o, 16);
            s1 += __shfl_down(s1, o, 16);
        }
        if (part == 0) {
            out[(size_t)(b0 + r) * 2 + 0] = s0 + bV[0];
            out[(size_t)(b0 + r) * 2 + 1] = s1 + bV[1];
        }
    }
}

extern "C" void kernel_launch(void* const* d_in, const int* in_sizes, int n_in,
                              void* d_out, int out_size, void* d_ws, size_t ws_size,
                              hipStream_t stream) {
    const int*   x   = (const int*)d_in[0];
    const float* emb = (const float*)d_in[1];
    const float* W   = (const float*)d_in[2];
    const float* U   = (const float*)d_in[3];
    const float* bU  = (const float*)d_in[4];
    const float* V   = (const float*)d_in[5];
    const float* bV  = (const float*)d_in[6];
    float* out = (float*)d_out;
    u16*   xw  = (u16*)d_ws;   // 64 MiB fp16 scratch, sigma-permuted columns

    embed_proj<<<BB * SB / TPB, 256, 0, stream>>>(x, emb, W, bU, xw);
    rnn_scan_mfma<<<BB / ROWS, 512, 0, stream>>>(xw, U, V, bV, out);
}